// Round 6
// baseline (317.308 us; speedup 1.0000x reference)
//
#include <hip/hip_runtime.h>
#include <cstdint>
#include <cstddef>

// Problem constants
#define B_    4
#define L_    4096
#define D_    1024
#define H_    16
#define HD_   64
#define ND3_  3072          // 3*D
#define M1_   16384         // B*L
#define NCH_  64            // number of chunks
#define CSZ_  64            // chunk size
#define SCALE_ 0.125f       // 1/sqrt(HD)

typedef __attribute__((ext_vector_type(8))) __bf16 bf16x8;
typedef __attribute__((ext_vector_type(4))) float f32x4;
typedef __attribute__((ext_vector_type(4))) unsigned int uint4v;

__device__ __forceinline__ float u2f(unsigned int u) { return __builtin_bit_cast(float, u); }
__device__ __forceinline__ unsigned int f2u(float f) { return __builtin_bit_cast(unsigned int, f); }
__device__ __forceinline__ float bf2f(unsigned short s) { return u2f(((unsigned int)s) << 16); }
__device__ __forceinline__ unsigned short f2bf(float f) {
  unsigned int u = f2u(f);
  u = u + 0x7fffu + ((u >> 16) & 1u);   // RNE
  return (unsigned short)(u >> 16);
}

// async global->LDS, 16B per lane. LDS dest wave-uniform base (+lane*16 implicit).
__device__ __forceinline__ void glds16(const unsigned short* g, unsigned short* l) {
  __builtin_amdgcn_global_load_lds(
      (const __attribute__((address_space(1))) void*)(uintptr_t)g,
      (__attribute__((address_space(3))) void*)(uintptr_t)l, 16, 0, 0);
}

// ---------------- fp32 -> bf16 cast ----------------
__global__ __launch_bounds__(256) void cast_kernel(const float* __restrict__ in,
                                                   unsigned short* __restrict__ out, int n)
{
  int i = (blockIdx.x * 256 + threadIdx.x) * 4;
  if (i + 3 < n) {
    float4 f = *(const float4*)(in + i);
    out[i + 0] = f2bf(f.x);
    out[i + 1] = f2bf(f.y);
    out[i + 2] = f2bf(f.z);
    out[i + 3] = f2bf(f.w);
  }
}

// ------------- bf16 NT GEMM, A via LDS / B via registers-from-L2: C = A @ Bm^T + bias ----
// 256x256 tile, BK=32, 512 threads = 8 waves (2M x 4N), per-wave C = 128x64.
// LDS holds ONLY A (triple buffer, 3x16KB): per CU per K-tile LDS = 16KB wr + 64KB rd
// = 625 cyc @128B/cyc < MFMA 1031 cyc (round-5 had 128KB = 1024 cyc -> LDS-BW-bound).
// B fragments stream global->VGPR (weights, L2-resident; bn-major XCD chunking keeps
// each XCD's B window <= 1MB < 4MB L2). B regs double-buffered via manual 2x unroll.
// FIFO vmcnt bookkeeping: per iter issues loadB(t+1) [4 loads] THEN stageA(t+2) [2 glds]
// (order pinned by sched_barrier). Top-of-iter queue = [A(t)x2, B(t)x4, A(t+1)x2];
// s_waitcnt vmcnt(2) drains exactly {A(t), B(t)}, keeps A(t+1) flying. Never 0 mid-loop.
// EPI 0: scatter into q/k/v (B,H,L,HD) bf16 with k*SCALE.  EPI 1: fp32 C out.
template<int EPI, int BM, int BN, int WM, int WN, int THREADS>
__global__ __launch_bounds__(THREADS, 2)
void gemm_breg(const unsigned short* __restrict__ A, const unsigned short* __restrict__ Bm,
               const float* __restrict__ bias,
               unsigned short* __restrict__ qo, unsigned short* __restrict__ ko,
               unsigned short* __restrict__ vo,
               float* __restrict__ Co, int M, int N, int K)
{
  constexpr int TR = THREADS / 4;     // rows covered per glds round (=128)
  constexpr int AR = BM / TR;         // glds rounds for A per K-tile (=2)
  constexpr int FM = BM / WM / 16;    // m-frags per wave (=8)
  constexpr int FN = BN / WN / 16;    // n-frags per wave (=4)
  constexpr int ASZ = BM * 32;

  __shared__ __align__(16) unsigned short Ab[3 * ASZ];

  // XCD-chunked swizzle; bn-major decode so same-XCD blocks share the B panel (L2-fit).
  const int nwg = gridDim.x;
  const int wg = (blockIdx.x & 7) * (nwg >> 3) + (blockIdx.x >> 3);
  const int nbm = M / BM;
  const int bm = wg % nbm, bn = wg / nbm;
  const int m0 = bm * BM, n0 = bn * BN;
  const int tid = threadIdx.x;
  const int lane = tid & 63, wid = tid >> 6;
  const int wr = wid / WN, wc = wid % WN;
  const int fl = lane & 15, fh = lane >> 4;

  // A staging lane constants (chunk-XOR swizzle, both sides)
  const int rowbase = wid * 16 + (lane >> 2);
  const int ckst = (lane & 3) ^ ((rowbase & 3) ^ ((rowbase >> 2) & 3));
  const int ckrd = fh ^ ((fl & 3) ^ ((fl >> 2) & 3));

  const int nt = K >> 5;   // must be even (K=1024 -> 32)

  f32x4 acc[FM][FN] = {};

  // per-lane B row pointers (NT: B-frag = rows of Bm)
  const unsigned short* bp[FN];
#pragma unroll
  for (int n = 0; n < FN; ++n)
    bp[n] = Bm + (size_t)(n0 + wc * (BN / WN) + n * 16 + fl) * K + fh * 8;

  auto stageA = [&](int kt, int d) {
#pragma unroll
    for (int s = 0; s < AR; ++s)
      glds16(A + (size_t)(m0 + s * TR + rowbase) * K + kt * 32 + ckst * 8,
             Ab + d * ASZ + s * TR * 32 + wid * 512);
  };

  uint4v rB0[FN], rB1[FN];

  // prologue: queue = [A0 x2, B0 x4, A1 x2]
  stageA(0, 0);
  __builtin_amdgcn_sched_barrier(0);
#pragma unroll
  for (int n = 0; n < FN; ++n) rB0[n] = *(const uint4v*)(bp[n]);
  __builtin_amdgcn_sched_barrier(0);
  stageA(1, 1);
  __builtin_amdgcn_sched_barrier(0);

  auto iter = [&](int t, uint4v (&rcur)[FN], uint4v (&rnxt)[FN]) {
    if (t < nt - 1) { asm volatile("s_waitcnt vmcnt(2)" ::: "memory"); }
    else            { asm volatile("s_waitcnt vmcnt(0)" ::: "memory"); }
    __builtin_amdgcn_s_barrier();
    __builtin_amdgcn_sched_barrier(0);

    const unsigned short* Abuf = Ab + (t % 3) * ASZ;

    // issue next-tile B loads (must precede stageA glds in the vmem FIFO)
    if (t + 1 < nt) {
#pragma unroll
      for (int n = 0; n < FN; ++n)
        rnxt[n] = *(const uint4v*)(bp[n] + (size_t)(t + 1) * 32);
    }
    // A frags first half
    bf16x8 afrag[FM / 2];
#pragma unroll
    for (int m = 0; m < FM / 2; ++m)
      afrag[m] = *(const bf16x8*)(Abuf + (wr * (BM / WM) + m * 16 + fl) * 32 + ckrd * 8);
    __builtin_amdgcn_sched_barrier(0);
    if (t + 2 < nt) stageA(t + 2, (t + 2) % 3);
    __builtin_amdgcn_sched_barrier(0);
    asm volatile("s_waitcnt lgkmcnt(0)" ::: "memory");
    __builtin_amdgcn_sched_barrier(0);
    __builtin_amdgcn_s_setprio(1);
#pragma unroll
    for (int m = 0; m < FM / 2; ++m)
#pragma unroll
      for (int n = 0; n < FN; ++n)
        acc[m][n] = __builtin_amdgcn_mfma_f32_16x16x32_bf16(
            afrag[m], __builtin_bit_cast(bf16x8, rcur[n]), acc[m][n], 0, 0, 0);
    __builtin_amdgcn_s_setprio(0);

    // A frags second half
    bf16x8 afrag2[FM / 2];
#pragma unroll
    for (int m = 0; m < FM / 2; ++m)
      afrag2[m] = *(const bf16x8*)(Abuf + (wr * (BM / WM) + (m + FM / 2) * 16 + fl) * 32 + ckrd * 8);
    asm volatile("s_waitcnt lgkmcnt(0)" ::: "memory");
    __builtin_amdgcn_sched_barrier(0);
    __builtin_amdgcn_s_setprio(1);
#pragma unroll
    for (int m = 0; m < FM / 2; ++m)
#pragma unroll
      for (int n = 0; n < FN; ++n)
        acc[m + FM / 2][n] = __builtin_amdgcn_mfma_f32_16x16x32_bf16(
            afrag2[m], __builtin_bit_cast(bf16x8, rcur[n]), acc[m + FM / 2][n], 0, 0, 0);
    __builtin_amdgcn_s_setprio(0);
  };

  for (int tt = 0; tt < nt; tt += 2) {   // nt even; named B-reg sets, no dynamic index
    iter(tt + 0, rB0, rB1);
    iter(tt + 1, rB1, rB0);
  }

  // epilogue: C row_local = (lane>>4)*4 + r, col_local = lane&15  [guide §3, m89]
  const int rb = fh << 2;
#pragma unroll
  for (int m = 0; m < FM; ++m) {
#pragma unroll
    for (int n = 0; n < FN; ++n) {
#pragma unroll
      for (int r = 0; r < 4; ++r) {
        int row = m0 + wr * (BM / WM) + m * 16 + rb + r;
        int col = n0 + wc * (BN / WN) + n * 16 + fl;
        float val = acc[m][n][r] + bias[col];
        if constexpr (EPI == 0) {
          int which = col >> 10;          // n / 1024
          int hh = (col >> 6) & 15;       // (n/64)%16
          int hd = col & 63;
          int bb = row >> 12;             // row / L
          int tt2 = row & 4095;
          size_t idx = (((size_t)(bb * H_ + hh)) * L_ + tt2) * HD_ + hd;
          if (which == 0)      qo[idx] = f2bf(val);
          else if (which == 1) ko[idx] = f2bf(val * SCALE_);
          else                 vo[idx] = f2bf(val);
        } else {
          Co[(size_t)row * N + col] = val;
        }
      }
    }
  }
}

// ---------------- retention phase 1 (MFMA): A_c[a][b] = sum_j g^{63-j} v_j[a] k_j[b] ----------------
__global__ __launch_bounds__(256) void ret_phase1(
    const unsigned short* __restrict__ kb, const unsigned short* __restrict__ vb,
    const float* __restrict__ gamma_raw, unsigned short* __restrict__ Sbuf)
{
  int bhc = blockIdx.x;
  int c = bhc & 63, bh = bhc >> 6, h = bh & 15;
  float g = 1.f / (1.f + expf(-gamma_raw[h]));
  float lg2g = log2f(g);

  __shared__ __align__(16) unsigned short Kt[64][72];   // Kt[b][j] = K[j][b]
  __shared__ __align__(16) unsigned short Vwt[64][72];  // Vwt[a][j] = g^{63-j} V[j][a]

  int tid = threadIdx.x;
  size_t base = ((size_t)bh * L_ + (size_t)c * CSZ_) * HD_;
#pragma unroll
  for (int qq = 0; qq < 16; ++qq) {
    int e = tid + qq * 256;
    int j = e >> 6, col = e & 63;
    float wj = exp2f(lg2g * (float)(63 - j));
    Kt[col][j] = kb[base + e];
    Vwt[col][j] = f2bf(bf2f(vb[base + e]) * wj);
  }
  __syncthreads();

  int lane = tid & 63, w = tid >> 6;
  int fl = lane & 15, fh = lane >> 4;

  bf16x8 av0 = *(const bf16x8*)(&Vwt[w * 16 + fl][fh * 8]);
  bf16x8 av1 = *(const bf16x8*)(&Vwt[w * 16 + fl][32 + fh * 8]);

  int rb = fh << 2;
  unsigned short* out = Sbuf + (size_t)bhc * 4096;
#pragma unroll
  for (int jf = 0; jf < 4; ++jf) {
    bf16x8 bk0 = *(const bf16x8*)(&Kt[jf * 16 + fl][fh * 8]);
    bf16x8 bk1 = *(const bf16x8*)(&Kt[jf * 16 + fl][32 + fh * 8]);
    f32x4 z = {};
    z = __builtin_amdgcn_mfma_f32_16x16x32_bf16(av0, bk0, z, 0, 0, 0);
    z = __builtin_amdgcn_mfma_f32_16x16x32_bf16(av1, bk1, z, 0, 0, 0);
#pragma unroll
    for (int r = 0; r < 4; ++r) {
      int a = w * 16 + rb + r, bcol = jf * 16 + fl;
      out[a * 64 + bcol] = f2bf(z[r]);
    }
  }
}

// ---------------- retention phase 2: in-place decay scan over chunks (bf16 storage) ----------------
__global__ __launch_bounds__(256) void ret_phase2(unsigned short* __restrict__ Sbuf,
                                                  const float* __restrict__ gamma_raw)
{
  int bh = blockIdx.x >> 3, grp = blockIdx.x & 7;
  int h = bh & 15;
  float g = 1.f / (1.f + expf(-gamma_raw[h]));
  float gC = powf(g, 64.f);
  int e = (grp * 256 + threadIdx.x) * 2;
  unsigned short* base = Sbuf + (size_t)bh * (NCH_ * 4096) + e;
  float s0 = 0.f, s1 = 0.f;
  for (int c = 0; c < NCH_; ++c) {
    unsigned int u = *(unsigned int*)(base + (size_t)c * 4096);
    float a0 = bf2f((unsigned short)(u & 0xffffu));
    float a1 = bf2f((unsigned short)(u >> 16));
    *(unsigned int*)(base + (size_t)c * 4096) =
        (unsigned int)f2bf(s0) | ((unsigned int)f2bf(s1) << 16);
    s0 = gC * s0 + a0;
    s1 = gC * s1 + a1;
  }
}

// ---------------- retention phase 3 (MFMA): Y = (D ∘ QK^T) V + g^{i+1} (Q S^T) ----------------
__global__ __launch_bounds__(256) void ret_phase3(
    const unsigned short* __restrict__ qb, const unsigned short* __restrict__ kb,
    const unsigned short* __restrict__ vb, const unsigned short* __restrict__ Sbuf,
    const float* __restrict__ gamma_raw, unsigned short* __restrict__ y)
{
  int bhc = blockIdx.x;
  int c = bhc & 63, bh = bhc >> 6, h = bh & 15, b = bh >> 4;
  float g = 1.f / (1.f + expf(-gamma_raw[h]));
  float lg2g = log2f(g);

  __shared__ __align__(16) unsigned short Qs[64][72];
  __shared__ __align__(16) unsigned short Ks[64][72];
  __shared__ __align__(16) unsigned short Vt[64][72];  // Vt[a][j] = V[j][a]
  __shared__ __align__(16) unsigned short Sb[64][72];  // S rows (bf16)
  __shared__ __align__(16) unsigned short Ps[64][72];  // masked P (bf16)

  int tid = threadIdx.x;
  size_t base = ((size_t)bh * L_ + (size_t)c * CSZ_) * HD_;
  const unsigned short* Sp = Sbuf + (size_t)bhc * 4096;
#pragma unroll
  for (int qq = 0; qq < 16; ++qq) {
    int e = tid + qq * 256;
    int r = e >> 6, col = e & 63;
    Qs[r][col] = qb[base + e];
    Ks[r][col] = kb[base + e];
    Vt[col][r] = vb[base + e];
    Sb[r][col] = Sp[e];
  }
  __syncthreads();

  int lane = tid & 63, w = tid >> 6;
  int fl = lane & 15, fh = lane >> 4;
  int rb = fh << 2;

  bf16x8 aq0 = *(const bf16x8*)(&Qs[w * 16 + fl][fh * 8]);
  bf16x8 aq1 = *(const bf16x8*)(&Qs[w * 16 + fl][32 + fh * 8]);

  f32x4 pc[4], acc[4];
#pragma unroll
  for (int jf = 0; jf < 4; ++jf) {
    bf16x8 bk0 = *(const bf16x8*)(&Ks[jf * 16 + fl][fh * 8]);
    bf16x8 bk1 = *(const bf16x8*)(&Ks[jf * 16 + fl][32 + fh * 8]);
    f32x4 z = {};
    z = __builtin_amdgcn_mfma_f32_16x16x32_bf16(aq0, bk0, z, 0, 0, 0);
    z = __builtin_amdgcn_mfma_f32_16x16x32_bf16(aq1, bk1, z, 0, 0, 0);
    pc[jf] = z;

    bf16x8 bs0 = *(const bf16x8*)(&Sb[jf * 16 + fl][fh * 8]);
    bf16x8 bs1 = *(const bf16x8*)(&Sb[jf * 16 + fl][32 + fh * 8]);
    f32x4 zz = {};
    zz = __builtin_amdgcn_mfma_f32_16x16x32_bf16(aq0, bs0, zz, 0, 0, 0);
    zz = __builtin_amdgcn_mfma_f32_16x16x32_bf16(aq1, bs1, zz, 0, 0, 0);
    acc[jf] = zz;
  }

#pragma unroll
  for (int jf = 0; jf < 4; ++jf) {
#pragma unroll
    for (int r = 0; r < 4; ++r) {
      int i = w * 16 + rb + r, j = jf * 16 + fl;
      float val = (j <= i) ? pc[jf][r] * exp2f(lg2g * (float)(i - j)) : 0.f;
      Ps[i][j] = f2bf(val);
    }
  }

  float gi1[4];
#pragma unroll
  for (int r = 0; r < 4; ++r) gi1[r] = exp2f(lg2g * (float)(w * 16 + rb + r + 1));
#pragma unroll
  for (int jf = 0; jf < 4; ++jf)
#pragma unroll
    for (int r = 0; r < 4; ++r) acc[jf][r] *= gi1[r];

  __syncthreads();

  bf16x8 ap0 = *(const bf16x8*)(&Ps[w * 16 + fl][fh * 8]);
  bf16x8 ap1 = *(const bf16x8*)(&Ps[w * 16 + fl][32 + fh * 8]);
#pragma unroll
  for (int jf = 0; jf < 4; ++jf) {
    bf16x8 bv0 = *(const bf16x8*)(&Vt[jf * 16 + fl][fh * 8]);
    bf16x8 bv1 = *(const bf16x8*)(&Vt[jf * 16 + fl][32 + fh * 8]);
    acc[jf] = __builtin_amdgcn_mfma_f32_16x16x32_bf16(ap0, bv0, acc[jf], 0, 0, 0);
    acc[jf] = __builtin_amdgcn_mfma_f32_16x16x32_bf16(ap1, bv1, acc[jf], 0, 0, 0);
  }

  size_t yrow = ((size_t)(b * L_ + c * CSZ_)) * D_ + h * HD_;
#pragma unroll
  for (int jf = 0; jf < 4; ++jf) {
#pragma unroll
    for (int r = 0; r < 4; ++r) {
      int i = w * 16 + rb + r;
      y[yrow + (size_t)i * D_ + jf * 16 + fl] = f2bf(acc[jf][r]);
    }
  }
}

// ---------------- launch ----------------
extern "C" void kernel_launch(void* const* d_in, const int* in_sizes, int n_in,
                              void* d_out, int out_size, void* d_ws, size_t ws_size,
                              hipStream_t stream)
{
  const float* x        = (const float*)d_in[0];
  const float* Wqkv_w   = (const float*)d_in[1];
  const float* Wqkv_b   = (const float*)d_in[2];
  const float* out_w    = (const float*)d_in[3];
  const float* out_b    = (const float*)d_in[4];
  const float* gamma_raw= (const float*)d_in[5];
  float* out = (float*)d_out;

  // workspace carve-up (~210 MB)
  char* ws = (char*)d_ws;
  unsigned short* x_bf    = (unsigned short*)ws; ws += (size_t)16777216 * 2;
  unsigned short* wqkv_bf = (unsigned short*)ws; ws += (size_t)3145728 * 2;
  unsigned short* wout_bf = (unsigned short*)ws; ws += (size_t)1048576 * 2;
  unsigned short* qb      = (unsigned short*)ws; ws += (size_t)16777216 * 2;
  unsigned short* kb      = (unsigned short*)ws; ws += (size_t)16777216 * 2;
  unsigned short* vb      = (unsigned short*)ws; ws += (size_t)16777216 * 2;
  unsigned short* Sbuf    = (unsigned short*)ws; ws += (size_t)16777216 * 2;
  unsigned short* yb      = (unsigned short*)ws; ws += (size_t)16777216 * 2;

  cast_kernel<<<16384, 256, 0, stream>>>(x, x_bf, 16777216);
  cast_kernel<<<3072, 256, 0, stream>>>(Wqkv_w, wqkv_bf, 3145728);
  cast_kernel<<<1024, 256, 0, stream>>>(out_w, wout_bf, 1048576);

  // qkv = x @ Wqkv^T + b  -> q/k/v (B,H,L,HD), k pre-scaled.  grid 768 (%8==0)
  gemm_breg<0, 256, 256, 2, 4, 512><<<64 * 12, 512, 0, stream>>>(
      x_bf, wqkv_bf, Wqkv_b, qb, kb, vb, nullptr, M1_, ND3_, D_);

  ret_phase1<<<4096, 256, 0, stream>>>(kb, vb, gamma_raw, Sbuf);
  ret_phase2<<<512, 256, 0, stream>>>(Sbuf, gamma_raw);
  ret_phase3<<<4096, 256, 0, stream>>>(qb, kb, vb, Sbuf, gamma_raw, yb);

  // out = y @ out_w^T + out_b  (fp32 out).  grid 256 (%8==0)
  gemm_breg<1, 256, 256, 2, 4, 512><<<64 * 4, 512, 0, stream>>>(
      yb, wout_bf, out_b, nullptr, nullptr, nullptr, out, M1_, D_, D_);
}